// Round 7
// baseline (242.410 us; speedup 1.0000x reference)
//
#include <hip/hip_runtime.h>
#include <cmath>

#define N_ 32
#define B_ 64
#define T_ 8192
#define NBLK1 1024             // 16 c-groups (512 t) * 64 b ; bid = cg*64 + b
#define PS 2176                // 2048 gram (pp|pn) + 128 stats

typedef _Float16 half8 __attribute__((ext_vector_type(8)));
typedef float floatx4 __attribute__((ext_vector_type(4)));

// async global->LDS DMA: 16 B per lane, dest = wave-uniform LDS base + lane*16,
// source = per-lane global address. Queue depth lives in vmcnt, NOT in VGPRs --
// this is the mechanism every previous round lacked (compiler clamped VGPR-held
// loads to ~2 convoys of 8; four different kernels all plateaued at 47-53us).
__device__ __forceinline__ void gload16(const float* g, void* lds) {
    __builtin_amdgcn_global_load_lds(
        (const __attribute__((address_space(1))) void*)g,
        (__attribute__((address_space(3))) void*)lds, 16, 0, 0);
}

// ---------------- Stage 1: global_load_lds-staged f32 tile -> MFMA ------------
// grid 1024 = 16 cg (512 t) * 64 b; block 512 (8 waves); 2 phases of 256 t.
// Per phase: 8 DMA instrs/wave (64/block, 1 KB each) fill tile[2][32][256] f32
// linearly; barrier (vmcnt drain hidden by the co-resident block's compute);
// stats via bank-perfect contiguous wave sweeps; MFMA reads f32 frags
// (2-way-aliased ds_read_b128 = free) + in-register cvt to f16.
__global__ __launch_bounds__(512, 4)
void k_stage1(const float* __restrict__ pos, const float* __restrict__ neg,
              float* __restrict__ partial, double* __restrict__ accs,
              unsigned* __restrict__ ctr) {
    __shared__ __align__(16) float tile[2][32][256];   // 65536 B
    const int bid = blockIdx.x;
    const int b = bid & 63, cg = bid >> 6;      // bid = cg*64 + b
    const int tid = threadIdx.x;
    const int w = tid >> 6, lane = tid & 63;    // 8 waves
    const int m = lane & 15, h = lane >> 4;     // A-frag coords
    const int mat = w >> 2, qi = (w >> 1) & 1, qj = w & 1;
    const int arow = qi * 16 + m, brow = qj * 16 + m;

    if (bid == 0 && tid == 0) { accs[0] = 0.0; accs[1] = 0.0; *ctr = 0u; }

    floatx4 acc = {};
    float s1[8], s2[8];
#pragma unroll
    for (int j = 0; j < 8; ++j) { s1[j] = 0.f; s2[j] = 0.f; }

    const long tb0 = (long)cg * 512;

#pragma unroll
    for (int ck = 0; ck < 2; ++ck) {
        // ---- stage this 256-t chunk: 8 x 1KB DMA per wave, zero VGPR cost
#pragma unroll
        for (int i = 0; i < 8; ++i) {
            const int lin = w * 8 + i;              // tensor = lin>>5, row = lin&31
            const int r = lin & 31;
            const float* base = (lin & 32) ? neg : pos;
            const float* src = base + ((long)r * B_ + b) * T_ + tb0 + ck * 256 + lane * 4;
            gload16(src, (char*)tile + (long)lin * 1024);
        }
        __syncthreads();   // compiler drains vmcnt before s_barrier -> tile ready

        // ---- stats: wave w sweeps rows w*8..w*8+7; each read = contiguous 1KB
#pragma unroll
        for (int j = 0; j < 8; ++j) {
            const float4* rp = (const float4*)((char*)tile + (long)(w * 8 + j) * 1024);
            float4 q = rp[lane];
            s1[j] += q.x + q.y + q.z + q.w;
            s2[j] = fmaf(q.x, q.x, s2[j]); s2[j] = fmaf(q.y, q.y, s2[j]);
            s2[j] = fmaf(q.z, q.z, s2[j]); s2[j] = fmaf(q.w, q.w, s2[j]);
        }

        // ---- MFMA: 8 K=32 steps over this chunk (acc carries across phases)
#pragma unroll
        for (int kk = 0; kk < 8; ++kk) {
            const float* ta = &tile[0][arow][kk * 32 + h * 8];
            const float* tb = &tile[mat][brow][kk * 32 + h * 8];
            float4 a0 = *(const float4*)ta, a1 = *(const float4*)(ta + 4);
            float4 b0 = *(const float4*)tb, b1 = *(const float4*)(tb + 4);
            half8 af = {(_Float16)a0.x, (_Float16)a0.y, (_Float16)a0.z, (_Float16)a0.w,
                        (_Float16)a1.x, (_Float16)a1.y, (_Float16)a1.z, (_Float16)a1.w};
            half8 bf = {(_Float16)b0.x, (_Float16)b0.y, (_Float16)b0.z, (_Float16)b0.w,
                        (_Float16)b1.x, (_Float16)b1.y, (_Float16)b1.z, (_Float16)b1.w};
            // mfma(rowfragX, rowfragY) = X . Y^T  (verified quadrant mapping)
            acc = __builtin_amdgcn_mfma_f32_16x16x32_f16(af, bf, acc, 0, 0, 0);
        }
        __syncthreads();   // all reads done before the next chunk's DMA lands
    }

    float* out = partial + (long)bid * PS;

    // ---- gram epilogue: C/D layout (m89-verified): col=lane&15, row=(lane>>4)*4+reg
#pragma unroll
    for (int reg = 0; reg < 4; ++reg) {
        const int rr = qi * 16 + h * 4 + reg;
        const int cc = qj * 16 + m;
        out[mat * 1024 + rr * 32 + cc] = acc[reg];
    }

    // ---- stats epilogue: full-wave butterfly, then lane j stores row w*8+j
#pragma unroll
    for (int j = 0; j < 8; ++j) {
        s1[j] += __shfl_xor(s1[j], 1);  s1[j] += __shfl_xor(s1[j], 2);
        s1[j] += __shfl_xor(s1[j], 4);  s1[j] += __shfl_xor(s1[j], 8);
        s1[j] += __shfl_xor(s1[j], 16); s1[j] += __shfl_xor(s1[j], 32);
        s2[j] += __shfl_xor(s2[j], 1);  s2[j] += __shfl_xor(s2[j], 2);
        s2[j] += __shfl_xor(s2[j], 4);  s2[j] += __shfl_xor(s2[j], 8);
        s2[j] += __shfl_xor(s2[j], 16); s2[j] += __shfl_xor(s2[j], 32);
    }
    float v1 = s1[0], v2 = s2[0];
#pragma unroll
    for (int j = 1; j < 8; ++j)
        if (lane == j) { v1 = s1[j]; v2 = s2[j]; }   // static idx, cndmask select
    if (lane < 8) {
        const int tr = w * 8 + lane;                  // tensor = tr>>5, row = tr&31
        out[2048 + (tr >> 5) * 64 + (tr & 31)] = v1;
        out[2048 + (tr >> 5) * 64 + 32 + (tr & 31)] = v2;
    }
}

// ---------------- Stage 2: reduce 16 chunk partials -> per-b stats (coalesced) ----
__global__ void k_reduce(const float* __restrict__ partial, float* __restrict__ red) {
    const int b = blockIdx.y;
    const int o = blockIdx.x * 128 + threadIdx.x;   // 0..2175
    float s = 0.f;
#pragma unroll
    for (int c = 0; c < 16; ++c) s += partial[(long)(c * 64 + b) * PS + o];
    red[(long)b * PS + o] = s;
}

// ---------------- Stage 3 (fused): pearson + exp + block sums + final ----------
__global__ __launch_bounds__(256)
void k_entries(const float* __restrict__ red, double* __restrict__ accs,
               unsigned* __restrict__ ctr, float* __restrict__ out) {
    const int tid = threadIdx.x;
    const int w = tid >> 6, lane = tid & 63;
    const int entry = blockIdx.x * 4 + w;
    const int mat = entry >> 10;        // 0 = pp, 1 = pn
    const int idx = entry & 1023;
    const int n = idx >> 5, m = idx & 31;

    const float* rb = red + (long)lane * PS;
    const float g    = rb[mat * 1024 + idx];
    const float sxn  = rb[2048 + n];
    const float sx2n = rb[2080 + n];
    const float sym  = rb[mat ? 2112 + m : 2048 + m];
    const float sy2m = rb[mat ? 2144 + m : 2080 + m];

    double num = (double)T_ * (double)g - (double)sxn * (double)sym;
    double vx = (double)T_ * (double)sx2n - (double)sxn * (double)sxn;
    double vy = (double)T_ * (double)sy2m - (double)sym * (double)sym;
    double contrib = 1.0 - num / sqrt(vx * vy);

#pragma unroll
    for (int off = 32; off; off >>= 1) contrib += __shfl_down(contrib, off);

    __shared__ double s_pos[4], s_neg[4];
    if (lane == 0) {
        double d = contrib * (1.0 / B_);
        double term = exp(d / 0.08);
        double p = 0.0, q = 0.0;
        if (mat == 0) { if (n < m) p = term; }   // strict upper triangle
        else q = term;
        s_pos[w] = p; s_neg[w] = q;
    }
    __syncthreads();
    if (tid == 0) {
        atomicAdd(&accs[0], s_pos[0] + s_pos[1] + s_pos[2] + s_pos[3]);
        atomicAdd(&accs[1], s_neg[0] + s_neg[1] + s_neg[2] + s_neg[3]);
        __threadfence();
        const unsigned old = atomicAdd(ctr, 1u);
        if (old == gridDim.x - 1) {              // last block finalizes
            __threadfence();
            const double p = ((volatile double*)accs)[0];
            const double q = ((volatile double*)accs)[1];
            out[0] = (float)log10(p / q + 1.0);
        }
    }
}

extern "C" void kernel_launch(void* const* d_in, const int* in_sizes, int n_in,
                              void* d_out, int out_size, void* d_ws, size_t ws_size,
                              hipStream_t stream) {
    (void)in_sizes; (void)n_in; (void)out_size; (void)ws_size;
    const float* pos = (const float*)d_in[0];
    const float* neg = (const float*)d_in[1];
    float* out = (float*)d_out;

    char* ws = (char*)d_ws;
    float* partial = (float*)ws;                               // 1024*2176*4 = 8,912,896 B
    float* red = (float*)(ws + (size_t)NBLK1 * PS * 4);        //   64*2176*4 =   557,056 B
    double* accs = (double*)(ws + (size_t)NBLK1 * PS * 4 + (size_t)64 * PS * 4);
    unsigned* ctr = (unsigned*)((char*)accs + 16);

    k_stage1<<<NBLK1, 512, 0, stream>>>(pos, neg, partial, accs, ctr);
    k_reduce<<<dim3(17, 64), 128, 0, stream>>>(partial, red);
    k_entries<<<512, 256, 0, stream>>>(red, accs, ctr, out);
}

// Round 8
// 183.480 us; speedup vs baseline: 1.3212x; 1.3212x over previous
//
#include <hip/hip_runtime.h>
#include <cmath>

#define N_ 32
#define B_ 64
#define T_ 8192
#define NBLK1 1024             // 16 c-groups (512 t) * 64 b ; bid = cg*64 + b
#define PS 2176                // 2048 gram (pp|pn) + 128 stats

typedef _Float16 half8 __attribute__((ext_vector_type(8)));
typedef float floatx4 __attribute__((ext_vector_type(4)));

// async global->LDS DMA: 16 B per lane, dest = wave-uniform LDS base + lane*16,
// source = per-lane global address (so swizzled LDS layouts are achieved by
// pre-swizzling the SOURCE address while keeping the LDS dest linear -- m173).
__device__ __forceinline__ void gload16(const float* g, void* lds) {
    __builtin_amdgcn_global_load_lds(
        (const __attribute__((address_space(1))) void*)g,
        (__attribute__((address_space(3))) void*)lds, 16, 0, 0);
}

// ---------------- Stage 1: DMA-staged f32 tile (XOR-swizzled) -> MFMA ---------
// Round-7 post-mortem: 45.6M LDS bank-conflict cycles (= the whole 51->118us
// regression) from reading 1024B-stride rows unswizzled (16-way conflict).
// Fix (rule #21, both-sides-or-neither): global_load_lds writes LINEAR, so the
// swizzle byte^=((row&7)<<4) is applied by permuting the per-lane GLOBAL source
// (lane ^= row&7 within each 1KB row chunk) and XORing the ds_read addresses.
// Fragment reads then hit 8 distinct 4-bank groups (2-way alias = free, m136).
// Stats sweeps read the permuted row contiguously (sum is perm-invariant).
__global__ __launch_bounds__(512, 4)
void k_stage1(const float* __restrict__ pos, const float* __restrict__ neg,
              float* __restrict__ partial, double* __restrict__ accs,
              unsigned* __restrict__ ctr) {
    __shared__ __align__(16) float tile[2][32][256];   // 65536 B
    const int bid = blockIdx.x;
    const int b = bid & 63, cg = bid >> 6;      // bid = cg*64 + b
    const int tid = threadIdx.x;
    const int w = tid >> 6, lane = tid & 63;    // 8 waves
    const int m = lane & 15, h = lane >> 4;     // A-frag coords
    const int mat = w >> 2, qi = (w >> 1) & 1, qj = w & 1;
    const int arow = qi * 16 + m, brow = qj * 16 + m;

    if (bid == 0 && tid == 0) { accs[0] = 0.0; accs[1] = 0.0; *ctr = 0u; }

    floatx4 acc = {};
    float s1[8], s2[8];
#pragma unroll
    for (int j = 0; j < 8; ++j) { s1[j] = 0.f; s2[j] = 0.f; }

    const long tb0 = (long)cg * 512;
    const char* tArow = (const char*)tile + (long)arow * 1024;           // tensor 0
    const char* tBrow = (const char*)tile + (long)(mat * 32 + brow) * 1024;
    const int xa = (arow & 7) << 4, xb = (brow & 7) << 4;

#pragma unroll
    for (int ck = 0; ck < 2; ++ck) {
        // ---- stage this 256-t chunk: 8 x 1KB DMA per wave, zero VGPR cost.
        // Source lane permuted by row&7 -> LDS holds the row XOR-swizzled.
#pragma unroll
        for (int i = 0; i < 8; ++i) {
            const int lin = w * 8 + i;              // tensor = lin>>5, row = lin&31
            const int r = lin & 31;
            const float* base = (lin & 32) ? neg : pos;
            const float* src = base + ((long)r * B_ + b) * T_ + tb0 + ck * 256
                               + ((lane ^ (r & 7)) * 4);
            gload16(src, (char*)tile + (long)lin * 1024);
        }
        __syncthreads();   // compiler drains vmcnt before s_barrier -> tile ready

        // ---- stats: wave w sweeps rows w*8..w*8+7; contiguous 1KB (perm-invariant)
#pragma unroll
        for (int j = 0; j < 8; ++j) {
            const float4* rp = (const float4*)((char*)tile + (long)(w * 8 + j) * 1024);
            float4 q = rp[lane];
            s1[j] += q.x + q.y + q.z + q.w;
            s2[j] = fmaf(q.x, q.x, s2[j]); s2[j] = fmaf(q.y, q.y, s2[j]);
            s2[j] = fmaf(q.z, q.z, s2[j]); s2[j] = fmaf(q.w, q.w, s2[j]);
        }

        // ---- MFMA: 8 K=32 steps; fragment reads XOR-swizzled per 16B slot
#pragma unroll
        for (int kk = 0; kk < 8; ++kk) {
            const int o = kk * 128 + h * 32;        // byte offset within row
            float4 a0 = *(const float4*)(tArow + ((o) ^ xa));
            float4 a1 = *(const float4*)(tArow + ((o + 16) ^ xa));
            float4 b0 = *(const float4*)(tBrow + ((o) ^ xb));
            float4 b1 = *(const float4*)(tBrow + ((o + 16) ^ xb));
            half8 af = {(_Float16)a0.x, (_Float16)a0.y, (_Float16)a0.z, (_Float16)a0.w,
                        (_Float16)a1.x, (_Float16)a1.y, (_Float16)a1.z, (_Float16)a1.w};
            half8 bf = {(_Float16)b0.x, (_Float16)b0.y, (_Float16)b0.z, (_Float16)b0.w,
                        (_Float16)b1.x, (_Float16)b1.y, (_Float16)b1.z, (_Float16)b1.w};
            // mfma(rowfragX, rowfragY) = X . Y^T  (verified quadrant mapping)
            acc = __builtin_amdgcn_mfma_f32_16x16x32_f16(af, bf, acc, 0, 0, 0);
        }
        __syncthreads();   // all reads done before the next chunk's DMA lands
    }

    float* out = partial + (long)bid * PS;

    // ---- gram epilogue: C/D layout (m89-verified): col=lane&15, row=(lane>>4)*4+reg
#pragma unroll
    for (int reg = 0; reg < 4; ++reg) {
        const int rr = qi * 16 + h * 4 + reg;
        const int cc = qj * 16 + m;
        out[mat * 1024 + rr * 32 + cc] = acc[reg];
    }

    // ---- stats epilogue: full-wave butterfly, then lane j stores row w*8+j
#pragma unroll
    for (int j = 0; j < 8; ++j) {
        s1[j] += __shfl_xor(s1[j], 1);  s1[j] += __shfl_xor(s1[j], 2);
        s1[j] += __shfl_xor(s1[j], 4);  s1[j] += __shfl_xor(s1[j], 8);
        s1[j] += __shfl_xor(s1[j], 16); s1[j] += __shfl_xor(s1[j], 32);
        s2[j] += __shfl_xor(s2[j], 1);  s2[j] += __shfl_xor(s2[j], 2);
        s2[j] += __shfl_xor(s2[j], 4);  s2[j] += __shfl_xor(s2[j], 8);
        s2[j] += __shfl_xor(s2[j], 16); s2[j] += __shfl_xor(s2[j], 32);
    }
    float v1 = s1[0], v2 = s2[0];
#pragma unroll
    for (int j = 1; j < 8; ++j)
        if (lane == j) { v1 = s1[j]; v2 = s2[j]; }   // static idx, cndmask select
    if (lane < 8) {
        const int tr = w * 8 + lane;                  // tensor = tr>>5, row = tr&31
        out[2048 + (tr >> 5) * 64 + (tr & 31)] = v1;
        out[2048 + (tr >> 5) * 64 + 32 + (tr & 31)] = v2;
    }
}

// ---------------- Stage 2: reduce 16 chunk partials -> per-b stats (coalesced) ----
__global__ void k_reduce(const float* __restrict__ partial, float* __restrict__ red) {
    const int b = blockIdx.y;
    const int o = blockIdx.x * 128 + threadIdx.x;   // 0..2175
    float s = 0.f;
#pragma unroll
    for (int c = 0; c < 16; ++c) s += partial[(long)(c * 64 + b) * PS + o];
    red[(long)b * PS + o] = s;
}

// ---------------- Stage 3 (fused): pearson + exp + block sums + final ----------
__global__ __launch_bounds__(256)
void k_entries(const float* __restrict__ red, double* __restrict__ accs,
               unsigned* __restrict__ ctr, float* __restrict__ out) {
    const int tid = threadIdx.x;
    const int w = tid >> 6, lane = tid & 63;
    const int entry = blockIdx.x * 4 + w;
    const int mat = entry >> 10;        // 0 = pp, 1 = pn
    const int idx = entry & 1023;
    const int n = idx >> 5, m = idx & 31;

    const float* rb = red + (long)lane * PS;
    const float g    = rb[mat * 1024 + idx];
    const float sxn  = rb[2048 + n];
    const float sx2n = rb[2080 + n];
    const float sym  = rb[mat ? 2112 + m : 2048 + m];
    const float sy2m = rb[mat ? 2144 + m : 2080 + m];

    double num = (double)T_ * (double)g - (double)sxn * (double)sym;
    double vx = (double)T_ * (double)sx2n - (double)sxn * (double)sxn;
    double vy = (double)T_ * (double)sy2m - (double)sym * (double)sym;
    double contrib = 1.0 - num / sqrt(vx * vy);

#pragma unroll
    for (int off = 32; off; off >>= 1) contrib += __shfl_down(contrib, off);

    __shared__ double s_pos[4], s_neg[4];
    if (lane == 0) {
        double d = contrib * (1.0 / B_);
        double term = exp(d / 0.08);
        double p = 0.0, q = 0.0;
        if (mat == 0) { if (n < m) p = term; }   // strict upper triangle
        else q = term;
        s_pos[w] = p; s_neg[w] = q;
    }
    __syncthreads();
    if (tid == 0) {
        atomicAdd(&accs[0], s_pos[0] + s_pos[1] + s_pos[2] + s_pos[3]);
        atomicAdd(&accs[1], s_neg[0] + s_neg[1] + s_neg[2] + s_neg[3]);
        __threadfence();
        const unsigned old = atomicAdd(ctr, 1u);
        if (old == gridDim.x - 1) {              // last block finalizes
            __threadfence();
            const double p = ((volatile double*)accs)[0];
            const double q = ((volatile double*)accs)[1];
            out[0] = (float)log10(p / q + 1.0);
        }
    }
}

extern "C" void kernel_launch(void* const* d_in, const int* in_sizes, int n_in,
                              void* d_out, int out_size, void* d_ws, size_t ws_size,
                              hipStream_t stream) {
    (void)in_sizes; (void)n_in; (void)out_size; (void)ws_size;
    const float* pos = (const float*)d_in[0];
    const float* neg = (const float*)d_in[1];
    float* out = (float*)d_out;

    char* ws = (char*)d_ws;
    float* partial = (float*)ws;                               // 1024*2176*4 = 8,912,896 B
    float* red = (float*)(ws + (size_t)NBLK1 * PS * 4);        //   64*2176*4 =   557,056 B
    double* accs = (double*)(ws + (size_t)NBLK1 * PS * 4 + (size_t)64 * PS * 4);
    unsigned* ctr = (unsigned*)((char*)accs + 16);

    k_stage1<<<NBLK1, 512, 0, stream>>>(pos, neg, partial, accs, ctr);
    k_reduce<<<dim3(17, 64), 128, 0, stream>>>(partial, red);
    k_entries<<<512, 256, 0, stream>>>(red, accs, ctr, out);
}

// Round 9
// 179.820 us; speedup vs baseline: 1.3481x; 1.0204x over previous
//
#include <hip/hip_runtime.h>
#include <cmath>

#define N_ 32
#define B_ 64
#define T_ 8192
#define NS1 512                // stage1 grid: 8 t-slices * 64 b ; bid = sl*64 + b
#define PS 2176                // 2048 gram (pp|pn) + 128 stats

typedef _Float16 half8 __attribute__((ext_vector_type(8)));
typedef float floatx4 __attribute__((ext_vector_type(4)));

// async global->LDS DMA: dest = wave-uniform LDS base + lane*16 (linear);
// source = per-lane global address (pre-swizzled -> LDS holds XOR-swizzled rows).
__device__ __forceinline__ void gload16(const float* g, void* lds) {
    __builtin_amdgcn_global_load_lds(
        (const __attribute__((address_space(1))) void*)g,
        (__attribute__((address_space(3))) void*)lds, 16, 0, 0);
}

// ---------------- Stage 1: T3+T4 pipelined DMA staging -> MFMA ----------------
// Rounds 0-8 post-mortem: five structures, all 47-57us, all share ONE property:
// <=2 phases with a full vmcnt(0) drain at each barrier (the m97-structure
// stall). This version is the catalog's T3+T4 fix: 8 phases of 128 t, 2x32KB
// LDS double-buffer, counted s_waitcnt vmcnt(4) + RAW s_barrier so phase p+1's
// 4 DMA loads stay in flight across the barrier while phase p computes.
// Bank layout identical to round 8's verified-clean swizzle (2.1M conflicts).
__global__ __launch_bounds__(512, 4)
void k_stage1(const float* __restrict__ pos, const float* __restrict__ neg,
              float* __restrict__ partial, double* __restrict__ accs,
              unsigned* __restrict__ ctr) {
    __shared__ __align__(16) float tile[2][64][128];   // 2 bufs x 64 rows x 512 B
    const int bid = blockIdx.x;
    const int b = bid & 63, sl = bid >> 6;      // t-slice 0..7 (1024 t each)
    const int tid = threadIdx.x;
    const int w = tid >> 6, lane = tid & 63;    // 8 waves
    const int m = lane & 15, h = lane >> 4;     // A-frag coords
    const int mat = w >> 2, qi = (w >> 1) & 1, qj = w & 1;
    const int arow = qi * 16 + m, brow = qj * 16 + m;

    if (bid == 0 && tid == 0) { accs[0] = 0.0; accs[1] = 0.0; *ctr = 0u; }

    // per-lane DMA source geometry: wave w owns flat rows w*8..w*8+7
    // (flat = tensor*32 + row). Each DMA covers 2 rows (half-wave each).
    const int l31 = lane & 31, lh = lane >> 5;
    const long tb0 = (long)sl * 1024;

    floatx4 acc = {};
    float s1[4], s2[4];
#pragma unroll
    for (int j = 0; j < 4; ++j) { s1[j] = 0.f; s2[j] = 0.f; }

    const char* tbase = (const char*)tile;
    const char* tA0 = tbase + (long)arow * 512;            // tensor 0, buf 0
    const char* tB0 = tbase + (long)(mat * 32 + brow) * 512;
    const int xa = (arow & 7) << 4, xb = (brow & 7) << 4;

    // stage phase p into buffer (p&1): 4 DMA instrs per wave, zero VGPR cost
#define STAGE(p)                                                               \
    {                                                                          \
        const int _buf = (p) & 1;                                              \
        _Pragma("unroll")                                                      \
        for (int i = 0; i < 4; ++i) {                                          \
            const int lin0 = w * 8 + i * 2;                                    \
            const int lin = lin0 + lh;                                         \
            const int r = lin & 31;                                            \
            const float* base = (lin & 32) ? neg : pos;                        \
            const float* src = base + ((long)r * B_ + b) * T_ + tb0            \
                               + (p) * 128 + ((l31 ^ (r & 7)) * 4);            \
            gload16(src, (char*)tile + (long)_buf * 32768 + (long)lin0 * 512); \
        }                                                                      \
    }

    STAGE(0)
    STAGE(1)

#pragma unroll
    for (int p = 0; p < 8; ++p) {
        // counted wait: newest 4 (phase p+1) stay IN FLIGHT across the barrier
        if (p < 7) asm volatile("s_waitcnt vmcnt(4)" ::: "memory");
        else       asm volatile("s_waitcnt vmcnt(0)" ::: "memory");
        __builtin_amdgcn_s_barrier();    // raw: no compiler-forced full drain

        const char* bb = tbase + (long)(p & 1) * 32768;

        // ---- stats: 4 contiguous 1KB sweeps (rows w*8+2i | +2i+1 per half-wave)
#pragma unroll
        for (int i = 0; i < 4; ++i) {
            const float4* rp = (const float4*)(bb + (long)(w * 8 + i * 2) * 512);
            float4 q = rp[lane];
            s1[i] += q.x + q.y + q.z + q.w;
            s2[i] = fmaf(q.x, q.x, s2[i]); s2[i] = fmaf(q.y, q.y, s2[i]);
            s2[i] = fmaf(q.z, q.z, s2[i]); s2[i] = fmaf(q.w, q.w, s2[i]);
        }

        // ---- MFMA: K=128 -> 4 steps; fragment reads XOR-swizzled per 16B slot
        const char* tAr = tA0 + (long)(p & 1) * 32768;
        const char* tBr = tB0 + (long)(p & 1) * 32768;
#pragma unroll
        for (int kk = 0; kk < 4; ++kk) {
            const int o = kk * 128 + h * 32;
            float4 a0 = *(const float4*)(tAr + ((o) ^ xa));
            float4 a1 = *(const float4*)(tAr + ((o + 16) ^ xa));
            float4 b0 = *(const float4*)(tBr + ((o) ^ xb));
            float4 b1 = *(const float4*)(tBr + ((o + 16) ^ xb));
            half8 af = {(_Float16)a0.x, (_Float16)a0.y, (_Float16)a0.z, (_Float16)a0.w,
                        (_Float16)a1.x, (_Float16)a1.y, (_Float16)a1.z, (_Float16)a1.w};
            half8 bf = {(_Float16)b0.x, (_Float16)b0.y, (_Float16)b0.z, (_Float16)b0.w,
                        (_Float16)b1.x, (_Float16)b1.y, (_Float16)b1.z, (_Float16)b1.w};
            // mfma(rowfragX, rowfragY) = X . Y^T  (verified quadrant mapping)
            acc = __builtin_amdgcn_mfma_f32_16x16x32_f16(af, bf, acc, 0, 0, 0);
        }

        __builtin_amdgcn_s_barrier();    // all waves done READING buf (p&1)
        if (p + 2 < 8) STAGE(p + 2)      // refill the freed buffer
    }
#undef STAGE

    float* out = partial + (long)bid * PS;

    // ---- gram epilogue: C/D layout (m89-verified): col=lane&15, row=(lane>>4)*4+reg
#pragma unroll
    for (int reg = 0; reg < 4; ++reg) {
        const int rr = qi * 16 + h * 4 + reg;
        const int cc = qj * 16 + m;
        out[mat * 1024 + rr * 32 + cc] = acc[reg];
    }

    // ---- stats epilogue: butterfly within each 32-lane half (rows differ by half)
#pragma unroll
    for (int i = 0; i < 4; ++i) {
        s1[i] += __shfl_xor(s1[i], 1);  s1[i] += __shfl_xor(s1[i], 2);
        s1[i] += __shfl_xor(s1[i], 4);  s1[i] += __shfl_xor(s1[i], 8);
        s1[i] += __shfl_xor(s1[i], 16);
        s2[i] += __shfl_xor(s2[i], 1);  s2[i] += __shfl_xor(s2[i], 2);
        s2[i] += __shfl_xor(s2[i], 4);  s2[i] += __shfl_xor(s2[i], 8);
        s2[i] += __shfl_xor(s2[i], 16);
    }
    if (l31 == 0) {   // lanes 0 (even rows) and 32 (odd rows) store
#pragma unroll
        for (int i = 0; i < 4; ++i) {
            const int tr = w * 8 + i * 2 + lh;    // flat row; tensor = tr>>5
            out[2048 + (tr >> 5) * 64 + (tr & 31)] = s1[i];
            out[2048 + (tr >> 5) * 64 + 32 + (tr & 31)] = s2[i];
        }
    }
}

// ---------------- Stage 2: reduce 8 slice partials -> per-b stats (coalesced) ----
__global__ void k_reduce(const float* __restrict__ partial, float* __restrict__ red) {
    const int b = blockIdx.y;
    const int o = blockIdx.x * 128 + threadIdx.x;   // 0..2175
    float s = 0.f;
#pragma unroll
    for (int c = 0; c < 8; ++c) s += partial[(long)(c * 64 + b) * PS + o];
    red[(long)b * PS + o] = s;
}

// ---------------- Stage 3 (fused): pearson + exp + block sums + final ----------
__global__ __launch_bounds__(256)
void k_entries(const float* __restrict__ red, double* __restrict__ accs,
               unsigned* __restrict__ ctr, float* __restrict__ out) {
    const int tid = threadIdx.x;
    const int w = tid >> 6, lane = tid & 63;
    const int entry = blockIdx.x * 4 + w;
    const int mat = entry >> 10;        // 0 = pp, 1 = pn
    const int idx = entry & 1023;
    const int n = idx >> 5, m = idx & 31;

    const float* rb = red + (long)lane * PS;
    const float g    = rb[mat * 1024 + idx];
    const float sxn  = rb[2048 + n];
    const float sx2n = rb[2080 + n];
    const float sym  = rb[mat ? 2112 + m : 2048 + m];
    const float sy2m = rb[mat ? 2144 + m : 2080 + m];

    double num = (double)T_ * (double)g - (double)sxn * (double)sym;
    double vx = (double)T_ * (double)sx2n - (double)sxn * (double)sxn;
    double vy = (double)T_ * (double)sy2m - (double)sym * (double)sym;
    double contrib = 1.0 - num / sqrt(vx * vy);

#pragma unroll
    for (int off = 32; off; off >>= 1) contrib += __shfl_down(contrib, off);

    __shared__ double s_pos[4], s_neg[4];
    if (lane == 0) {
        double d = contrib * (1.0 / B_);
        double term = exp(d / 0.08);
        double p = 0.0, q = 0.0;
        if (mat == 0) { if (n < m) p = term; }   // strict upper triangle
        else q = term;
        s_pos[w] = p; s_neg[w] = q;
    }
    __syncthreads();
    if (tid == 0) {
        atomicAdd(&accs[0], s_pos[0] + s_pos[1] + s_pos[2] + s_pos[3]);
        atomicAdd(&accs[1], s_neg[0] + s_neg[1] + s_neg[2] + s_neg[3]);
        __threadfence();
        const unsigned old = atomicAdd(ctr, 1u);
        if (old == gridDim.x - 1) {              // last block finalizes
            __threadfence();
            const double p = ((volatile double*)accs)[0];
            const double q = ((volatile double*)accs)[1];
            out[0] = (float)log10(p / q + 1.0);
        }
    }
}

extern "C" void kernel_launch(void* const* d_in, const int* in_sizes, int n_in,
                              void* d_out, int out_size, void* d_ws, size_t ws_size,
                              hipStream_t stream) {
    (void)in_sizes; (void)n_in; (void)out_size; (void)ws_size;
    const float* pos = (const float*)d_in[0];
    const float* neg = (const float*)d_in[1];
    float* out = (float*)d_out;

    char* ws = (char*)d_ws;
    float* partial = (float*)ws;                               // 512*2176*4 = 4,456,448 B
    float* red = (float*)(ws + (size_t)NS1 * PS * 4);          //  64*2176*4 =   557,056 B
    double* accs = (double*)(ws + (size_t)NS1 * PS * 4 + (size_t)64 * PS * 4);
    unsigned* ctr = (unsigned*)((char*)accs + 16);

    k_stage1<<<NS1, 512, 0, stream>>>(pos, neg, partial, accs, ctr);
    k_reduce<<<dim3(17, 64), 128, 0, stream>>>(partial, red);
    k_entries<<<512, 256, 0, stream>>>(red, accs, ctr, out);
}